// Round 7
// baseline (174.037 us; speedup 1.0000x reference)
//
#include <hip/hip_runtime.h>
#include <hip/hip_bf16.h>
#include <math.h>

typedef unsigned short ushort_t;
typedef __attribute__((ext_vector_type(8))) short short8;
typedef __attribute__((ext_vector_type(4))) short short4v;
typedef __attribute__((ext_vector_type(4))) float float4v;

#define NN 4096
#define BB 4
#define CC 64
#define ICH 32
#define SPLITS 4
#define KSPAN (NN / SPLITS)  // 1024 K rows per split

// workspace layout (float offsets); total 4,030,592 floats = 16.1 MB
#define OFF_QB 0                       // ushort[524288]
#define OFF_KB 262144                  // ushort[524288]
#define OFF_VT 524288                  // ushort[524288] (V transposed [b][i][n])
#define OFF_OP 786432                  // fp32 [b][s][n][ich] = 2097152
#define OFF_LS 2883584                 // fp32 [b][s][n] = 65536
#define OFF_WY 2949120                 // fp32 [b][c][n] = 1048576
#define OFF_SP 3997696                 // fp32 [2][64][256] = 32768
#define OFF_AB 4030464                 // fp32 [128]

static __device__ __forceinline__ ushort_t f2b(float f) {
  union { float f; unsigned u; } v;
  v.f = f;
  return (ushort_t)((v.u + 0x8000u) >> 16);
}

// ---------------------------------------------------------------------------
// Kernel 1: projections -> bf16.  Block = 64 n-rows of one batch b.
// Qb/Kb [b][n][i]; Vt [b][i][n] via LDS transpose (coalesced 8B stores).
// ---------------------------------------------------------------------------
__global__ __launch_bounds__(256) void proj_kernel(
    const float* __restrict__ xt, const float* __restrict__ xo,
    const float* __restrict__ gw, const float* __restrict__ gb,
    const float* __restrict__ tw, const float* __restrict__ tb,
    const float* __restrict__ pw, const float* __restrict__ pb,
    ushort_t* __restrict__ Qb, ushort_t* __restrict__ Kb,
    ushort_t* __restrict__ Vt) {
  __shared__ float wth[ICH * 65];
  __shared__ float wgg[ICH * 65];
  __shared__ float wph[ICH * 65];
  __shared__ float bth[ICH], bgg[ICH], bph[ICH];
  __shared__ float xs_t[64 * 64], xs_o[64 * 64];
  __shared__ ushort_t vt_l[ICH * 68];  // stride 68: conflict-free, 8B-aligned rows

  int t = threadIdx.x;
  int b = blockIdx.y;
  int n0 = blockIdx.x * 64;

  for (int l = t; l < ICH * CC; l += 256) {
    int i = l >> 6, c = l & 63;
    wth[i * 65 + c] = tw[l];
    wgg[i * 65 + c] = gw[l];
    wph[i * 65 + c] = pw[l];
  }
  if (t < ICH) {
    bth[t] = tb[t];
    bgg[t] = gb[t];
    bph[t] = pb[t];
  }
  for (int l = t; l < 64 * 64; l += 256) {
    int n = l >> 6, c = l & 63;
    size_t src = ((size_t)(n0 + n) * BB + b) * CC + c;
    xs_t[l] = xt[src];
    xs_o[l] = xo[src];
  }
  __syncthreads();

  int i = t & 31, h = t >> 5;  // i = out channel, h = n-group
#pragma unroll
  for (int k = 0; k < 8; k++) {
    int n = h * 8 + k;
    float at = bth[i], ag = bgg[i], ap = bph[i];
    for (int c = 0; c < CC; c++) {
      float xv = xs_t[n * 64 + c];
      float xvo = xs_o[n * 64 + c];
      at += wth[i * 65 + c] * xv;
      ag += wgg[i * 65 + c] * xv;
      ap += wph[i * 65 + c] * xvo;
    }
    size_t outi = ((size_t)b * NN + n0 + n) * ICH + i;
    Kb[outi] = f2b(at);
    Qb[outi] = f2b(ap);
    vt_l[i * 68 + n] = f2b(ag);
  }
  __syncthreads();
  // coalesced Vt store: 512 ushort4 chunks
#pragma unroll
  for (int l = t; l < 512; l += 256) {
    int ii = l >> 4, nq = l & 15;
    short4v v = *(const short4v*)(vt_l + ii * 68 + nq * 4);
    *(short4v*)(Vt + ((size_t)(b * ICH + ii)) * NN + n0 + nq * 4) = v;
  }
}

// ---------------------------------------------------------------------------
// Kernel 2: MFMA attention partials, K-split x4 (unnormalized exp -> additive
// partials).  Grid (NN/64, SPLITS, BB); WG = 4 waves; wave owns 16 Q rows.
// ---------------------------------------------------------------------------
__global__ __launch_bounds__(256) void attn_kernel(
    const ushort_t* __restrict__ Qb, const ushort_t* __restrict__ Kb,
    const ushort_t* __restrict__ Vt, float* __restrict__ OP,
    float* __restrict__ LS) {
  __shared__ ushort_t plds_all[4][16 * 36];

  int t = threadIdx.x;
  int wv = t >> 6, lane = t & 63;
  int l15 = lane & 15, quad = lane >> 4;
  int s = blockIdx.y, b = blockIdx.z;
  int q0 = blockIdx.x * 64 + wv * 16;

  ushort_t* plds = plds_all[wv];

  short8 qf = *(const short8*)(Qb + ((size_t)b * NN + q0 + l15) * ICH + quad * 8);

  float4v o0 = {0.f, 0.f, 0.f, 0.f};
  float4v o1 = {0.f, 0.f, 0.f, 0.f};
  float ls[4] = {0.f, 0.f, 0.f, 0.f};

  const ushort_t* Kbb = Kb + (size_t)b * NN * ICH;
  const ushort_t* Vtb = Vt + (size_t)b * ICH * NN;

  int mbeg = s * KSPAN;
#pragma unroll 2
  for (int m0 = mbeg; m0 < mbeg + KSPAN; m0 += 32) {
    const ushort_t* kp = Kbb + ((size_t)(m0 + l15)) * ICH + quad * 8;
    short8 kf0 = *(const short8*)(kp);
    short8 kf1 = *(const short8*)(kp + 16 * ICH);
    const ushort_t* vp = Vtb + (size_t)l15 * NN + m0 + quad * 8;
    short8 vf0 = *(const short8*)(vp);
    short8 vf1 = *(const short8*)(vp + 16 * NN);

    float4v z = {0.f, 0.f, 0.f, 0.f};
    float4v s0 = __builtin_amdgcn_mfma_f32_16x16x32_bf16(qf, kf0, z, 0, 0, 0);
    float4v s1 = __builtin_amdgcn_mfma_f32_16x16x32_bf16(qf, kf1, z, 0, 0, 0);

#pragma unroll
    for (int r = 0; r < 4; r++) {
      float p0 = __expf(fminf(s0[r], 60.f));
      float p1 = __expf(fminf(s1[r], 60.f));
      ls[r] += p0 + p1;
      plds[(quad * 4 + r) * 36 + l15] = f2b(p0);
      plds[(quad * 4 + r) * 36 + 16 + l15] = f2b(p1);
    }
    const ushort_t* pr = plds + l15 * 36 + quad * 8;
    short4v pa = *(const short4v*)(pr);
    short4v pb2 = *(const short4v*)(pr + 4);
    short8 pf = __builtin_shufflevector(pa, pb2, 0, 1, 2, 3, 4, 5, 6, 7);

    o0 = __builtin_amdgcn_mfma_f32_16x16x32_bf16(pf, vf0, o0, 0, 0, 0);
    o1 = __builtin_amdgcn_mfma_f32_16x16x32_bf16(pf, vf1, o1, 0, 0, 0);
  }

#pragma unroll
  for (int r = 0; r < 4; r++) {
    float v = ls[r];
    v += __shfl_xor(v, 1, 64);
    v += __shfl_xor(v, 2, 64);
    v += __shfl_xor(v, 4, 64);
    v += __shfl_xor(v, 8, 64);
    ls[r] = v;
  }

  size_t base = (size_t)(b * SPLITS + s) * NN;
#pragma unroll
  for (int r = 0; r < 4; r++) {
    int q = q0 + quad * 4 + r;
    float* op = OP + (base + q) * ICH;
    op[l15] = o0[r];
    op[16 + l15] = o1[r];
    if (l15 == 0) LS[base + q] = ls[r];
  }
}

// ---------------------------------------------------------------------------
// Kernel 3: combine splits + normalize + wz projection + BN stat partials.
// WY[b,c,n] = w_c . y[n,:] + bc ; SP[0][c][blk]=sum, SP[1][c][blk]=sumsq
// ---------------------------------------------------------------------------
__global__ __launch_bounds__(256) void wz_kernel(
    const float* __restrict__ OP, const float* __restrict__ LS,
    const float* __restrict__ wz_w, const float* __restrict__ wz_b,
    float* __restrict__ WY, float* __restrict__ SP) {
  __shared__ float yl[64 * 33];
  __shared__ float lsum[64];
  __shared__ float w[CC * ICH];
  __shared__ float bias[CC];
  __shared__ float wyl[64 * 65];
  __shared__ float red1[256], red2[256];

  int b = blockIdx.y, n0 = blockIdx.x * 64, t = threadIdx.x;
  int blkid = b * 64 + blockIdx.x;  // 256 blocks

  for (int l = t; l < CC * ICH; l += 256) w[l] = wz_w[l];
  if (t < CC) bias[t] = wz_b[t];
  if (t < 64) {
    float s = 0.f;
#pragma unroll
    for (int sp = 0; sp < SPLITS; sp++)
      s += LS[(size_t)(b * SPLITS + sp) * NN + n0 + t];
    lsum[t] = s;
  }
  __syncthreads();
#pragma unroll
  for (int it = 0; it < 8; it++) {
    int lin = it * 256 + t;
    int i = lin & 31, dn = lin >> 5;
    float s = 0.f;
#pragma unroll
    for (int sp = 0; sp < SPLITS; sp++)
      s += OP[((size_t)(b * SPLITS + sp) * NN + n0 + dn) * ICH + i];
    yl[dn * 33 + i] = s / lsum[dn];
  }
  __syncthreads();
#pragma unroll
  for (int it = 0; it < 16; it++) {
    int lin = it * 256 + t;
    int c = lin >> 6, dn = lin & 63;
    float acc = bias[c];
#pragma unroll
    for (int i = 0; i < ICH; i++) acc += w[c * 32 + i] * yl[dn * 33 + i];
    WY[((size_t)(b * CC + c)) * NN + n0 + dn] = acc;
    wyl[c * 65 + dn] = acc;
  }
  __syncthreads();
  {
    int c = t >> 2, part = t & 3;
    float s1 = 0.f, s2 = 0.f;
#pragma unroll
    for (int k = 0; k < 16; k++) {
      float v = wyl[c * 65 + part * 16 + k];
      s1 += v;
      s2 += v * v;
    }
    red1[t] = s1;
    red2[t] = s2;
  }
  __syncthreads();
  if (t < 64) {
    float s1 = red1[t * 4] + red1[t * 4 + 1] + red1[t * 4 + 2] + red1[t * 4 + 3];
    float s2 = red2[t * 4] + red2[t * 4 + 1] + red2[t * 4 + 2] + red2[t * 4 + 3];
    SP[t * 256 + blkid] = s1;
    SP[64 * 256 + t * 256 + blkid] = s2;
  }
}

// ---------------------------------------------------------------------------
// Kernel 4: final BN stats (64 threads, double, deterministic)
// ---------------------------------------------------------------------------
__global__ __launch_bounds__(64) void stats_kernel(
    const float* __restrict__ SP, const float* __restrict__ gamma,
    const float* __restrict__ beta, float* __restrict__ AB) {
  int t = threadIdx.x;
  double s1 = 0.0, s2 = 0.0;
  for (int k = 0; k < 256; k++) {
    s1 += (double)SP[t * 256 + k];
    s2 += (double)SP[64 * 256 + t * 256 + k];
  }
  double inv = 1.0 / (double)(BB * NN);
  double mean = s1 * inv;
  double var = s2 * inv - mean * mean;
  if (var < 0.0) var = 0.0;
  double rstd = 1.0 / sqrt(var + 1e-5);
  float A = gamma[t] * (float)rstd;
  AB[t] = A;
  AB[64 + t] = beta[t] - (float)mean * A;
}

// ---------------------------------------------------------------------------
// Kernel 5: normalize + residual -> fp32 out (B,C,N)
// ---------------------------------------------------------------------------
__global__ __launch_bounds__(256) void norm_kernel(
    const float* __restrict__ WY, const float* __restrict__ AB,
    const float* __restrict__ xthis, float* __restrict__ out) {
  __shared__ float xl[64 * 65];
  __shared__ float abr[128];
  int b = blockIdx.y, n0 = blockIdx.x * 64, t = threadIdx.x;
  if (t < 128) abr[t] = AB[t];
#pragma unroll
  for (int it = 0; it < 16; it++) {
    int lin = it * 256 + t;
    int c = lin & 63, dn = lin >> 6;
    xl[dn * 65 + c] = xthis[((size_t)(n0 + dn) * BB + b) * CC + c];
  }
  __syncthreads();
#pragma unroll
  for (int it = 0; it < 16; it++) {
    int lin = it * 256 + t;
    int c = lin >> 6, dn = lin & 63;
    size_t idx = ((size_t)(b * CC + c)) * NN + n0 + dn;
    out[idx] = WY[idx] * abr[c] + abr[64 + c] + xl[dn * 65 + c];
  }
}

// ---------------------------------------------------------------------------
extern "C" void kernel_launch(void* const* d_in, const int* in_sizes, int n_in,
                              void* d_out, int out_size, void* d_ws,
                              size_t ws_size, hipStream_t stream) {
  const float* x_this = (const float*)d_in[0];
  const float* x_other = (const float*)d_in[1];
  const float* g_w = (const float*)d_in[2];
  const float* g_b = (const float*)d_in[3];
  const float* th_w = (const float*)d_in[4];
  const float* th_b = (const float*)d_in[5];
  const float* ph_w = (const float*)d_in[6];
  const float* ph_b = (const float*)d_in[7];
  const float* wz_w = (const float*)d_in[8];
  const float* wz_b = (const float*)d_in[9];
  const float* gamma = (const float*)d_in[10];
  const float* beta = (const float*)d_in[11];
  float* out = (float*)d_out;

  float* ws = (float*)d_ws;
  ushort_t* Qb = (ushort_t*)(ws + OFF_QB);
  ushort_t* Kb = (ushort_t*)(ws + OFF_KB);
  ushort_t* Vt = (ushort_t*)(ws + OFF_VT);
  float* OP = ws + OFF_OP;
  float* LS = ws + OFF_LS;
  float* WY = ws + OFF_WY;
  float* SP = ws + OFF_SP;
  float* AB = ws + OFF_AB;

  hipLaunchKernelGGL(proj_kernel, dim3(NN / 64, BB), dim3(256), 0, stream,
                     x_this, x_other, g_w, g_b, th_w, th_b, ph_w, ph_b,
                     Qb, Kb, Vt);
  hipLaunchKernelGGL(attn_kernel, dim3(NN / 64, SPLITS, BB), dim3(256), 0,
                     stream, Qb, Kb, Vt, OP, LS);
  hipLaunchKernelGGL(wz_kernel, dim3(NN / 64, BB), dim3(256), 0, stream,
                     OP, LS, wz_w, wz_b, WY, SP);
  hipLaunchKernelGGL(stats_kernel, dim3(1), dim3(64), 0, stream,
                     SP, gamma, beta, AB);
  hipLaunchKernelGGL(norm_kernel, dim3(NN / 64, BB), dim3(256), 0, stream,
                     WY, AB, x_this, out);
}

// Round 8
// 167.026 us; speedup vs baseline: 1.0420x; 1.0420x over previous
//
#include <hip/hip_runtime.h>
#include <hip/hip_bf16.h>
#include <math.h>

typedef unsigned short ushort_t;
typedef __attribute__((ext_vector_type(8))) short short8;
typedef __attribute__((ext_vector_type(4))) short short4v;
typedef __attribute__((ext_vector_type(4))) float float4v;

#define NN 4096
#define BB 4
#define CC 64
#define ICH 32
#define SPLITS 4
#define KSPAN (NN / SPLITS)  // 1024 K rows per split

// workspace layout (float offsets); total 4,030,592 floats = 16.1 MB
#define OFF_QB 0                       // ushort[524288]  Q bf16 [b][n][i]
#define OFF_KB 262144                  // ushort[524288]  K bf16 [b][n][i]
#define OFF_VT 524288                  // ushort[524288]  V bf16 [b][i][n]
#define OFF_OP 786432                  // fp32 [b][s][n][ich] = 2097152
#define OFF_LS 2883584                 // fp32 [b][s][n] = 65536
#define OFF_WY 2949120                 // fp32 [b][c][n] = 1048576
#define OFF_SP 3997696                 // fp32 [2][256 blk][64 c] = 32768
#define OFF_AB 4030464                 // fp32 [128]

static __device__ __forceinline__ ushort_t f2b(float f) {
  union { float f; unsigned u; } v;
  v.f = f;
  return (ushort_t)((v.u + 0x8000u) >> 16);
}

// load 8 consecutive fp32, convert to bf16x8 (MFMA frag register layout)
static __device__ __forceinline__ short8 cvt8(const float* p) {
  float4 a = *(const float4*)p;
  float4 b = *(const float4*)(p + 4);
  short8 r;
  r[0] = (short)f2b(a.x); r[1] = (short)f2b(a.y);
  r[2] = (short)f2b(a.z); r[3] = (short)f2b(a.w);
  r[4] = (short)f2b(b.x); r[5] = (short)f2b(b.y);
  r[6] = (short)f2b(b.z); r[7] = (short)f2b(b.w);
  return r;
}

// ---------------------------------------------------------------------------
// Kernel 1: projections via MFMA (the 1x1 convs ARE a GEMM).
// Block = 64 n-rows of batch b; wave = 16 rows.  A = x rows (bf16 from
// global), B = W^T (bf16 from global), bias in acc init.
// Outputs: Kb/Qb [b][n][i]; Vt [b][i][n] via LDS transpose tile.
// ---------------------------------------------------------------------------
__global__ __launch_bounds__(256) void proj_kernel(
    const float* __restrict__ xt, const float* __restrict__ xo,
    const float* __restrict__ gw, const float* __restrict__ gb,
    const float* __restrict__ tw, const float* __restrict__ tb,
    const float* __restrict__ pw, const float* __restrict__ pb,
    ushort_t* __restrict__ Qb, ushort_t* __restrict__ Kb,
    ushort_t* __restrict__ Vt) {
  __shared__ ushort_t vt_l[ICH * 68];  // [i][n_local 0..63], pad 68

  int t = threadIdx.x;
  int wv = t >> 6, lane = t & 63, l15 = lane & 15, quad = lane >> 4;
  int b = blockIdx.y;
  int n0w = blockIdx.x * 64 + wv * 16;  // n base for this wave

  // A-frags: x[(n0w+l15) th row of batch b], c = quad*8..+8 (+32)
  const float* xrt = xt + ((size_t)(n0w + l15) * BB + b) * CC;
  const float* xro = xo + ((size_t)(n0w + l15) * BB + b) * CC;
  short8 at0 = cvt8(xrt + quad * 8);
  short8 at1 = cvt8(xrt + 32 + quad * 8);
  short8 ao0 = cvt8(xro + quad * 8);
  short8 ao1 = cvt8(xro + 32 + quad * 8);

#pragma unroll
  for (int h = 0; h < 2; h++) {  // output-channel half: i = h*16 + l15
    int i = h * 16 + l15;
    // theta -> Kb
    {
      short8 b0 = cvt8(tw + (size_t)i * CC + quad * 8);
      short8 b1 = cvt8(tw + (size_t)i * CC + 32 + quad * 8);
      float bias = tb[i];
      float4v acc = {bias, bias, bias, bias};
      acc = __builtin_amdgcn_mfma_f32_16x16x32_bf16(at0, b0, acc, 0, 0, 0);
      acc = __builtin_amdgcn_mfma_f32_16x16x32_bf16(at1, b1, acc, 0, 0, 0);
#pragma unroll
      for (int r = 0; r < 4; r++)
        Kb[((size_t)b * NN + n0w + quad * 4 + r) * ICH + i] = f2b(acc[r]);
    }
    // phi -> Qb (uses x_other)
    {
      short8 b0 = cvt8(pw + (size_t)i * CC + quad * 8);
      short8 b1 = cvt8(pw + (size_t)i * CC + 32 + quad * 8);
      float bias = pb[i];
      float4v acc = {bias, bias, bias, bias};
      acc = __builtin_amdgcn_mfma_f32_16x16x32_bf16(ao0, b0, acc, 0, 0, 0);
      acc = __builtin_amdgcn_mfma_f32_16x16x32_bf16(ao1, b1, acc, 0, 0, 0);
#pragma unroll
      for (int r = 0; r < 4; r++)
        Qb[((size_t)b * NN + n0w + quad * 4 + r) * ICH + i] = f2b(acc[r]);
    }
    // g -> V (to LDS transpose tile)
    {
      short8 b0 = cvt8(gw + (size_t)i * CC + quad * 8);
      short8 b1 = cvt8(gw + (size_t)i * CC + 32 + quad * 8);
      float bias = gb[i];
      float4v acc = {bias, bias, bias, bias};
      acc = __builtin_amdgcn_mfma_f32_16x16x32_bf16(at0, b0, acc, 0, 0, 0);
      acc = __builtin_amdgcn_mfma_f32_16x16x32_bf16(at1, b1, acc, 0, 0, 0);
#pragma unroll
      for (int r = 0; r < 4; r++)
        vt_l[(size_t)i * 68 + wv * 16 + quad * 4 + r] = f2b(acc[r]);
    }
  }
  __syncthreads();
  // Vt store: thread -> (i, 8-n segment); 16B coalesced stores
  {
    int i = t & 31, seg = t >> 5;
    short8 v;
#pragma unroll
    for (int k = 0; k < 8; k++) v[k] = (short)vt_l[i * 68 + seg * 8 + k];
    *(short8*)(Vt + (size_t)(b * ICH + i) * NN + blockIdx.x * 64 + seg * 8) = v;
  }
}

// ---------------------------------------------------------------------------
// Kernel 2: MFMA attention partials, K-split x4, software-pipelined:
// 64-kr iterations, K/V prefetch 1 iter ahead, dual P LDS buffers so
// PV(t) overlaps loads/QK of t+1.  Unnormalized exp (scores bounded).
// ---------------------------------------------------------------------------
__global__ __launch_bounds__(256) void attn_kernel(
    const ushort_t* __restrict__ Qb, const ushort_t* __restrict__ Kb,
    const ushort_t* __restrict__ Vt, float* __restrict__ OP,
    float* __restrict__ LS) {
  __shared__ ushort_t plds_all[4][2][16 * 68];  // per wave, dual buffer

  int t = threadIdx.x;
  int wv = t >> 6, lane = t & 63, l15 = lane & 15, quad = lane >> 4;
  int s = blockIdx.y, b = blockIdx.z;
  int q0 = blockIdx.x * 64 + wv * 16;

  ushort_t* P0 = plds_all[wv][0];
  ushort_t* P1 = plds_all[wv][1];

  short8 qf = *(const short8*)(Qb + ((size_t)b * NN + q0 + l15) * ICH + quad * 8);

  float4v o0 = {0.f, 0.f, 0.f, 0.f};
  float4v o1 = {0.f, 0.f, 0.f, 0.f};
  float ls[4] = {0.f, 0.f, 0.f, 0.f};

  const ushort_t* Kbb = Kb + (size_t)b * NN * ICH;
  const ushort_t* Vtb = Vt + (size_t)b * ICH * NN;
  int mbeg = s * KSPAN;

  short8 kf[2][4], vf[2][4];

  auto LOADKV = [&](int it, int pbuf) {
    int m0 = mbeg + it * 64;
    const ushort_t* kp = Kbb + (size_t)(m0 + l15) * ICH + quad * 8;
    kf[pbuf][0] = *(const short8*)(kp);
    kf[pbuf][1] = *(const short8*)(kp + 16 * ICH);
    kf[pbuf][2] = *(const short8*)(kp + 32 * ICH);
    kf[pbuf][3] = *(const short8*)(kp + 48 * ICH);
    const ushort_t* vp = Vtb + (size_t)l15 * NN + m0 + quad * 8;
    vf[pbuf][0] = *(const short8*)(vp);            // sub0, ch 0..15
    vf[pbuf][1] = *(const short8*)(vp + 16 * NN);  // sub0, ch 16..31
    vf[pbuf][2] = *(const short8*)(vp + 32);       // sub1, ch 0..15
    vf[pbuf][3] = *(const short8*)(vp + 32 + 16 * NN);
  };

  auto QKEXP = [&](int pbuf, ushort_t* P) {
    float4v z = {0.f, 0.f, 0.f, 0.f};
    float4v s00 = __builtin_amdgcn_mfma_f32_16x16x32_bf16(qf, kf[pbuf][0], z, 0, 0, 0);
    float4v s01 = __builtin_amdgcn_mfma_f32_16x16x32_bf16(qf, kf[pbuf][1], z, 0, 0, 0);
    float4v s10 = __builtin_amdgcn_mfma_f32_16x16x32_bf16(qf, kf[pbuf][2], z, 0, 0, 0);
    float4v s11 = __builtin_amdgcn_mfma_f32_16x16x32_bf16(qf, kf[pbuf][3], z, 0, 0, 0);
#pragma unroll
    for (int r = 0; r < 4; r++) {
      float p00 = __expf(fminf(s00[r], 60.f));
      float p01 = __expf(fminf(s01[r], 60.f));
      float p10 = __expf(fminf(s10[r], 60.f));
      float p11 = __expf(fminf(s11[r], 60.f));
      ls[r] += (p00 + p01) + (p10 + p11);
      ushort_t* row = P + (quad * 4 + r) * 68;
      row[l15] = f2b(p00);
      row[16 + l15] = f2b(p01);
      row[32 + l15] = f2b(p10);
      row[48 + l15] = f2b(p11);
    }
  };

  auto PV = [&](int pbuf, ushort_t* P) {
    const ushort_t* pr = P + l15 * 68 + quad * 8;
    short4v pa0 = *(const short4v*)(pr);
    short4v pa1 = *(const short4v*)(pr + 4);
    short8 pf0 = __builtin_shufflevector(pa0, pa1, 0, 1, 2, 3, 4, 5, 6, 7);
    short4v pb0 = *(const short4v*)(pr + 32);
    short4v pb1 = *(const short4v*)(pr + 36);
    short8 pf1 = __builtin_shufflevector(pb0, pb1, 0, 1, 2, 3, 4, 5, 6, 7);
    o0 = __builtin_amdgcn_mfma_f32_16x16x32_bf16(pf0, vf[pbuf][0], o0, 0, 0, 0);
    o1 = __builtin_amdgcn_mfma_f32_16x16x32_bf16(pf0, vf[pbuf][1], o1, 0, 0, 0);
    o0 = __builtin_amdgcn_mfma_f32_16x16x32_bf16(pf1, vf[pbuf][2], o0, 0, 0, 0);
    o1 = __builtin_amdgcn_mfma_f32_16x16x32_bf16(pf1, vf[pbuf][3], o1, 0, 0, 0);
  };

  LOADKV(0, 0);
  QKEXP(0, P0);
#pragma unroll
  for (int it = 0; it < 16; it++) {
    int cb = it & 1;
    if (it < 15) LOADKV(it + 1, cb ^ 1);
    PV(cb, cb ? P1 : P0);
    if (it < 15) QKEXP(cb ^ 1, cb ? P0 : P1);
  }

#pragma unroll
  for (int r = 0; r < 4; r++) {
    float v = ls[r];
    v += __shfl_xor(v, 1, 64);
    v += __shfl_xor(v, 2, 64);
    v += __shfl_xor(v, 4, 64);
    v += __shfl_xor(v, 8, 64);
    ls[r] = v;
  }

  size_t base = (size_t)(b * SPLITS + s) * NN;
#pragma unroll
  for (int r = 0; r < 4; r++) {
    int q = q0 + quad * 4 + r;
    float* op = OP + (base + q) * ICH;
    op[l15] = o0[r];
    op[16 + l15] = o1[r];
    if (l15 == 0) LS[base + q] = ls[r];
  }
}

// ---------------------------------------------------------------------------
// Kernel 3: combine splits + normalize + wz projection + BN stat partials.
// Thread owns fixed c (w row in 32 VGPRs), 16 n's; float4 LDS reads.
// SP layout [blk][c] (coalesced for stats kernel).
// ---------------------------------------------------------------------------
__global__ __launch_bounds__(256) void wz_kernel(
    const float* __restrict__ OP, const float* __restrict__ LS,
    const float* __restrict__ wz_w, const float* __restrict__ wz_b,
    float* __restrict__ WY, float* __restrict__ SP) {
  __shared__ float yl[64 * 36];  // [dn][i], pad 36 (16B aligned)
  __shared__ float lsum[64];
  __shared__ float red1[256], red2[256];

  int b = blockIdx.y, n0 = blockIdx.x * 64, t = threadIdx.x;
  int blkid = b * 64 + blockIdx.x;

  if (t < 64) {
    float ssum = 0.f;
#pragma unroll
    for (int sp = 0; sp < SPLITS; sp++)
      ssum += LS[(size_t)(b * SPLITS + sp) * NN + n0 + t];
    lsum[t] = ssum;
  }
  __syncthreads();
#pragma unroll
  for (int it = 0; it < 8; it++) {
    int lin = it * 256 + t;
    int i = lin & 31, dn = lin >> 5;
    float sacc = 0.f;
#pragma unroll
    for (int sp = 0; sp < SPLITS; sp++)
      sacc += OP[((size_t)(b * SPLITS + sp) * NN + n0 + dn) * ICH + i];
    yl[dn * 36 + i] = sacc / lsum[dn];
  }
  __syncthreads();

  int c = t >> 2, sub = t & 3;
  float4 w4[8];
#pragma unroll
  for (int j = 0; j < 8; j++) w4[j] = ((const float4*)(wz_w + c * ICH))[j];
  float bc = wz_b[c];
  float s1 = 0.f, s2 = 0.f;
#pragma unroll
  for (int d = 0; d < 16; d++) {
    int dn = sub * 16 + d;
    const float4* y4 = (const float4*)(yl + dn * 36);
    float acc = bc;
#pragma unroll
    for (int j = 0; j < 8; j++) {
      float4 y = y4[j];
      acc += w4[j].x * y.x + w4[j].y * y.y + w4[j].z * y.z + w4[j].w * y.w;
    }
    WY[((size_t)(b * CC + c)) * NN + n0 + dn] = acc;
    s1 += acc;
    s2 += acc * acc;
  }
  red1[t] = s1;
  red2[t] = s2;
  __syncthreads();
  if (t < 64) {
    float a1 = red1[t * 4] + red1[t * 4 + 1] + red1[t * 4 + 2] + red1[t * 4 + 3];
    float a2 = red2[t * 4] + red2[t * 4 + 1] + red2[t * 4 + 2] + red2[t * 4 + 3];
    SP[(size_t)blkid * 64 + t] = a1;
    SP[16384 + (size_t)blkid * 64 + t] = a2;
  }
}

// ---------------------------------------------------------------------------
// Kernel 4: final BN stats.  256 threads, coalesced SP reads, fp64
// deterministic reduce.  AB[c]=gamma*rstd; AB[64+c]=beta-mean*gamma*rstd.
// ---------------------------------------------------------------------------
__global__ __launch_bounds__(256) void stats_kernel(
    const float* __restrict__ SP, const float* __restrict__ gamma,
    const float* __restrict__ beta, float* __restrict__ AB) {
  __shared__ double rd1[256], rd2[256];
  int t = threadIdx.x, c = t & 63, part = t >> 6;
  double s1 = 0.0, s2 = 0.0;
  for (int k = part * 64; k < part * 64 + 64; k++) {
    s1 += (double)SP[(size_t)k * 64 + c];
    s2 += (double)SP[16384 + (size_t)k * 64 + c];
  }
  rd1[t] = s1;
  rd2[t] = s2;
  __syncthreads();
  if (t < 64) {
    double a1 = rd1[t] + rd1[64 + t] + rd1[128 + t] + rd1[192 + t];
    double a2 = rd2[t] + rd2[64 + t] + rd2[128 + t] + rd2[192 + t];
    double inv = 1.0 / (double)(BB * NN);
    double mean = a1 * inv;
    double var = a2 * inv - mean * mean;
    if (var < 0.0) var = 0.0;
    double rstd = 1.0 / sqrt(var + 1e-5);
    float A = gamma[t] * (float)rstd;
    AB[t] = A;
    AB[64 + t] = beta[t] - (float)mean * A;
  }
}

// ---------------------------------------------------------------------------
// Kernel 5: normalize + residual -> fp32 out (B,C,N)
// ---------------------------------------------------------------------------
__global__ __launch_bounds__(256) void norm_kernel(
    const float* __restrict__ WY, const float* __restrict__ AB,
    const float* __restrict__ xthis, float* __restrict__ out) {
  __shared__ float xl[64 * 65];
  __shared__ float abr[128];
  int b = blockIdx.y, n0 = blockIdx.x * 64, t = threadIdx.x;
  if (t < 128) abr[t] = AB[t];
#pragma unroll
  for (int it = 0; it < 16; it++) {
    int lin = it * 256 + t;
    int c = lin & 63, dn = lin >> 6;
    xl[dn * 65 + c] = xthis[((size_t)(n0 + dn) * BB + b) * CC + c];
  }
  __syncthreads();
#pragma unroll
  for (int it = 0; it < 16; it++) {
    int lin = it * 256 + t;
    int c = lin >> 6, dn = lin & 63;
    size_t idx = ((size_t)(b * CC + c)) * NN + n0 + dn;
    out[idx] = WY[idx] * abr[c] + abr[64 + c] + xl[dn * 65 + c];
  }
}

// ---------------------------------------------------------------------------
extern "C" void kernel_launch(void* const* d_in, const int* in_sizes, int n_in,
                              void* d_out, int out_size, void* d_ws,
                              size_t ws_size, hipStream_t stream) {
  const float* x_this = (const float*)d_in[0];
  const float* x_other = (const float*)d_in[1];
  const float* g_w = (const float*)d_in[2];
  const float* g_b = (const float*)d_in[3];
  const float* th_w = (const float*)d_in[4];
  const float* th_b = (const float*)d_in[5];
  const float* ph_w = (const float*)d_in[6];
  const float* ph_b = (const float*)d_in[7];
  const float* wz_w = (const float*)d_in[8];
  const float* wz_b = (const float*)d_in[9];
  const float* gamma = (const float*)d_in[10];
  const float* beta = (const float*)d_in[11];
  float* out = (float*)d_out;

  float* ws = (float*)d_ws;
  ushort_t* Qb = (ushort_t*)(ws + OFF_QB);
  ushort_t* Kb = (ushort_t*)(ws + OFF_KB);
  ushort_t* Vt = (ushort_t*)(ws + OFF_VT);
  float* OP = ws + OFF_OP;
  float* LS = ws + OFF_LS;
  float* WY = ws + OFF_WY;
  float* SP = ws + OFF_SP;
  float* AB = ws + OFF_AB;

  hipLaunchKernelGGL(proj_kernel, dim3(NN / 64, BB), dim3(256), 0, stream,
                     x_this, x_other, g_w, g_b, th_w, th_b, ph_w, ph_b,
                     Qb, Kb, Vt);
  hipLaunchKernelGGL(attn_kernel, dim3(NN / 64, SPLITS, BB), dim3(256), 0,
                     stream, Qb, Kb, Vt, OP, LS);
  hipLaunchKernelGGL(wz_kernel, dim3(NN / 64, BB), dim3(256), 0, stream,
                     OP, LS, wz_w, wz_b, WY, SP);
  hipLaunchKernelGGL(stats_kernel, dim3(1), dim3(256), 0, stream,
                     SP, gamma, beta, AB);
  hipLaunchKernelGGL(norm_kernel, dim3(NN / 64, BB), dim3(256), 0, stream,
                     WY, AB, x_this, out);
}